// Round 10
// baseline (365.424 us; speedup 1.0000x reference)
//
#include <hip/hip_runtime.h>
#include <hip/hip_cooperative_groups.h>
#include <math.h>

namespace cg = cooperative_groups;

typedef __attribute__((ext_vector_type(8))) short bf16x8;
typedef __attribute__((ext_vector_type(4))) float f32x4;

#define GRID 512

__device__ __forceinline__ ushort f2b(float f) {   // fp32 -> bf16 RNE
    unsigned u = __float_as_uint(f);
    return (ushort)((u + 0x7FFFu + ((u >> 16) & 1u)) >> 16);
}

// Direct global->LDS DMA, 16B per lane. LDS dest = uniform base + lane*16.
__device__ __forceinline__ void gl16(const ushort* g, ushort* l) {
    __builtin_amdgcn_global_load_lds((const __attribute__((address_space(1))) void*)g,
                                     (__attribute__((address_space(3))) void*)l, 16, 0, 0);
}

// Counted waits: every stage-pair = 4 DMA loads per wave, so vmcnt(4) waits
// for the older tile while the newer tile's 4 loads stay in flight (T4).
__device__ __forceinline__ void wait_pipe() { asm volatile("s_waitcnt vmcnt(4) lgkmcnt(0)" ::: "memory"); }
__device__ __forceinline__ void wait_all()  { asm volatile("s_waitcnt vmcnt(0) lgkmcnt(0)" ::: "memory"); }

// ---------------------------------------------------------------------------
// Tile staging: 64 rows x 64 bf16, row = 128B = 8 slots of 16B.
// Swizzle: LDS slot (r, s) holds logical col16 (s ^ (r&7)) [involution],
// applied on the global SOURCE address (LDS dest stays linear for DMA).
// ---------------------------------------------------------------------------
__device__ __forceinline__ void stage64(const ushort* g, int ld, ushort* lds,
                                        int w, int lane) {
    const int rsub = lane >> 3;
    const size_t coff = (size_t)(((lane & 7) ^ (rsub & 7)) * 8);
#pragma unroll
    for (int ii = 0; ii < 2; ++ii) {
        const int i = w * 2 + ii;
        gl16(g + (size_t)(i * 8 + rsub) * ld + coff, lds + i * 512);
    }
}

// Read one 16x32 MFMA operand fragment (row0 multiple of 16), k-half c of BK=64.
__device__ __forceinline__ bf16x8 frag(const ushort* lds, int row0, int c, int lane) {
    const int r = row0 + (lane & 15);
    const int slot = (c * 4 + (lane >> 4)) ^ (r & 7);
    return *(const bf16x8*)(lds + (size_t)r * 64 + slot * 8);
}

// 64x64 block, 4 waves (2x2), wave-tile 32x32 = 2x2 frags. 8 MFMA / step.
__device__ __forceinline__ void compute64(const ushort* As, const ushort* Bs,
                                          f32x4 acc[2][2], int lane, int wr, int wc) {
#pragma unroll
    for (int c = 0; c < 2; ++c) {
        bf16x8 a[2], b[2];
#pragma unroll
        for (int f = 0; f < 2; ++f) {
            a[f] = frag(As, wr * 32 + f * 16, c, lane);
            b[f] = frag(Bs, wc * 32 + f * 16, c, lane);
        }
#pragma unroll
        for (int i = 0; i < 2; ++i)
#pragma unroll
            for (int j = 0; j < 2; ++j)
                acc[i][j] = __builtin_amdgcn_mfma_f32_16x16x32_bf16(a[i], b[j], acc[i][j], 0, 0, 0);
    }
}

// 3-buffer counted-vmcnt pipelined 64x64 GEMM tile over NT K-steps of 64.
__device__ __forceinline__ void gemm_tile(const ushort* Ap, const ushort* Bp,
                                          int lda, int ldb, int NT, ushort* smem,
                                          f32x4 acc[2][2], int tid) {
    const int lane = tid & 63, w = tid >> 6, wr = w >> 1, wc = w & 1;
    stage64(Ap, lda, smem, w, lane);
    stage64(Bp, ldb, smem + 4096, w, lane);
    stage64(Ap + 64, lda, smem + 8192, w, lane);
    stage64(Bp + 64, ldb, smem + 8192 + 4096, w, lane);
    for (int t = 0; t < NT; ++t) {
        if (t < NT - 1) wait_pipe(); else wait_all();
        __builtin_amdgcn_s_barrier();
        __builtin_amdgcn_sched_barrier(0);
        if (t + 2 < NT) {
            ushort* nb = smem + ((t + 2) % 3) * 8192;
            stage64(Ap + (t + 2) * 64, lda, nb, w, lane);
            stage64(Bp + (t + 2) * 64, ldb, nb + 4096, w, lane);
        }
        const ushort* cb = smem + (t % 3) * 8192;
        compute64(cb, cb + 4096, acc, lane, wr, wc);
    }
}

// ---------------------------------------------------------------------------
// Single cooperative kernel: [qconsts+cvt] | qkv | scores | softmax | pv
// z_q(theta) = cos(theta)*A_q - sin(theta)*B_q collapses the quantum circuit;
// A_q=<Z_q>_psi0, B_q=<X_q>_psi0 computed per-block (2 regs/thread).
// ---------------------------------------------------------------------------
__global__ __launch_bounds__(256, 2) void fused_all(
        const float* __restrict__ x, const float* __restrict__ wq,
        const float* __restrict__ wk, const float* __restrict__ wv,
        const float* __restrict__ params, float* __restrict__ out,
        ushort* xb, ushort* wqb, ushort* wkb, ushort* wvb,
        ushort* qb, ushort* kb, ushort* vT, float* sb, ushort* wb) {
    __shared__ ushort smem[3 * 8192];    // 48 KB: 3 pipeline buffers (A|B halves)
    const int tid = threadIdx.x, bid = blockIdx.x;
    const int lane = tid & 63, wid = tid >> 6;
    cg::grid_group grid = cg::this_grid();

    // ---- phase 0a: quantum constants (every block, LDS aliased) ----
    float* stf  = (float*)smem;          // 256 floats
    float* redf = stf + 256;             // 64 floats
    float* abl  = redf + 64;             // 16 floats
    stf[tid] = (tid == 0) ? 1.0f : 0.0f;
    __syncthreads();
    for (int l = 0; l < 2; ++l) {
        for (int q = 0; q < 8; ++q) {
            float h = 0.5f * params[l * 8 + q];
            float c = cosf(h), s = sinf(h);
            int str = 1 << (7 - q);
            if ((tid & str) == 0) {
                float s0 = stf[tid], s1 = stf[tid + str];
                stf[tid]       = c * s0 - s * s1;
                stf[tid + str] = s * s0 + c * s1;
            }
            __syncthreads();
        }
        for (int q = 0; q < 8; ++q) {
            int tw = (q + 1) & 7;
            int cs = 1 << (7 - q), ts = 1 << (7 - tw);
            if ((tid & cs) && !(tid & ts)) {
                float a = stf[tid], b = stf[tid ^ ts];
                stf[tid] = b;
                stf[tid ^ ts] = a;
            }
            __syncthreads();
        }
    }
    const float amp = stf[tid];
    float qv[16];
#pragma unroll
    for (int q = 0; q < 8; ++q) {
        int str = 1 << (7 - q);
        qv[q]     = amp * amp * ((tid & str) ? -1.0f : 1.0f);
        qv[8 + q] = ((tid & str) == 0) ? 2.0f * amp * stf[tid ^ str] : 0.0f;
    }
#pragma unroll
    for (int off = 32; off; off >>= 1)
#pragma unroll
        for (int q = 0; q < 16; ++q) qv[q] += __shfl_xor(qv[q], off);
    if (lane == 0)
#pragma unroll
        for (int q = 0; q < 16; ++q) redf[wid * 16 + q] = qv[q];
    __syncthreads();
    if (tid < 16) abl[tid] = redf[tid] + redf[16 + tid] + redf[32 + tid] + redf[48 + tid];
    __syncthreads();
    const float Aq = abl[lane & 7], Bq = abl[8 + (lane & 7)];

    // ---- phase 0b: fp32 -> bf16 convert (grid-stride, 8 elems/chunk) ----
    const int CH = 131072 + 3 * 32768;   // x chunks + 3 W chunks
    for (int c = bid * 256 + tid; c < CH; c += GRID * 256) {
        const float* src; ushort* dst; int off;
        if (c < 131072) { src = x; dst = xb; off = c * 8; }
        else {
            int c2 = c - 131072;
            int wsel = c2 >> 15;
            off = (c2 & 32767) * 8;
            src = (wsel == 0) ? wq : (wsel == 1) ? wk : wv;
            dst = (wsel == 0) ? wqb : (wsel == 1) ? wkb : wvb;
        }
        float4 v0 = *(const float4*)(src + off);
        float4 v1 = *(const float4*)(src + off + 4);
        ushort t8[8] = {f2b(v0.x), f2b(v0.y), f2b(v0.z), f2b(v0.w),
                        f2b(v1.x), f2b(v1.y), f2b(v1.z), f2b(v1.w)};
        *(uint4*)(dst + off) = *(uint4*)t8;
    }
    grid.sync();

    // ---- phase 1: qkv (768 tiles; z=0/1: q,k = x.W^T; z=2: vT = Wv.x^T) ----
    for (int tt = bid; tt < 768; tt += GRID) {
        const int z = tt >> 8, r = tt & 255;
        int m0, n0, ldc;
        const ushort *Ap, *Bp;
        ushort* C;
        if (z < 2) {
            m0 = (r & 31) << 6;  n0 = (r >> 5) << 6;
            Ap = xb + (size_t)m0 * 512;
            Bp = (z ? wkb : wqb) + (size_t)n0 * 512;
            C = z ? kb : qb;  ldc = 512;
        } else {
            m0 = (r >> 5) << 6;  n0 = (r & 31) << 6;
            Ap = wvb + (size_t)m0 * 512;
            Bp = xb + (size_t)n0 * 512;
            C = vT;  ldc = 2048;
        }
        f32x4 acc[2][2] = {};
        gemm_tile(Ap, Bp, 512, 512, 8, smem, acc, tid);
        const int w = tid >> 6, wr = w >> 1, wc = w & 1;
        const int rb2 = (lane >> 4) << 2, cc = lane & 15;
#pragma unroll
        for (int fr = 0; fr < 2; ++fr)
#pragma unroll
            for (int fc = 0; fc < 2; ++fc) {
                int row = m0 + wr * 32 + fr * 16 + rb2;
                int col = n0 + wc * 32 + fc * 16 + cc;
#pragma unroll
                for (int rr = 0; rr < 4; ++rr)
                    C[(size_t)(row + rr) * ldc + col] = f2b(acc[fr][fc][rr]);
            }
        __syncthreads();
    }
    grid.sync();

    // ---- phase 2: scores (512 tiles exactly; S = q.k^T / sqrt(512)) ----
    {
        const int z = bid >> 8, r = bid & 255;
        const int m0 = (r & 15) << 6, n0 = (r >> 4) << 6;
        const ushort* Ap = qb + (size_t)z * 524288 + (size_t)m0 * 512;
        const ushort* Bp = kb + (size_t)z * 524288 + (size_t)n0 * 512;
        float* C = sb + (size_t)z * 1048576;
        f32x4 acc[2][2] = {};
        gemm_tile(Ap, Bp, 512, 512, 8, smem, acc, tid);
        const float scale = 0.044194173824159216f;   // 1/sqrt(512)
        const int w = tid >> 6, wr = w >> 1, wc = w & 1;
        const int rb2 = (lane >> 4) << 2, cc = lane & 15;
#pragma unroll
        for (int fr = 0; fr < 2; ++fr)
#pragma unroll
            for (int fc = 0; fc < 2; ++fc) {
                int row = m0 + wr * 32 + fr * 16 + rb2;
                int col = n0 + wc * 32 + fc * 16 + cc;
#pragma unroll
                for (int rr = 0; rr < 4; ++rr)
                    C[(size_t)(row + rr) * 1024 + col] = acc[fr][fc][rr] * scale;
            }
    }
    grid.sync();

    // ---- phase 3: softmax (4 rows per block), fp32 -> bf16 weights ----
    {
        float* sm = (float*)smem;
        float* ss = sm + 4;
        for (int row = bid; row < 2048; row += GRID) {
            const float* p = sb + (size_t)row * 1024;
            float4 v = ((const float4*)p)[tid];
            float m = fmaxf(fmaxf(v.x, v.y), fmaxf(v.z, v.w));
#pragma unroll
            for (int off = 32; off; off >>= 1) m = fmaxf(m, __shfl_xor(m, off));
            if (lane == 0) sm[wid] = m;
            __syncthreads();
            m = fmaxf(fmaxf(sm[0], sm[1]), fmaxf(sm[2], sm[3]));
            float e0 = expf(v.x - m), e1 = expf(v.y - m);
            float e2 = expf(v.z - m), e3 = expf(v.w - m);
            float s = e0 + e1 + e2 + e3;
#pragma unroll
            for (int off = 32; off; off >>= 1) s += __shfl_xor(s, off);
            if (lane == 0) ss[wid] = s;
            __syncthreads();
            s = ss[0] + ss[1] + ss[2] + ss[3];
            float rr = 1.0f / s;
            ushort4 o = {f2b(e0 * rr), f2b(e1 * rr), f2b(e2 * rr), f2b(e3 * rr)};
            ((ushort4*)(wb + (size_t)row * 1024))[tid] = o;
            __syncthreads();
        }
    }
    grid.sync();

    // ---- phase 4: pv (256 tiles) + quantum epilogue ----
    if (bid < 256) {
        const int z = bid >> 7, r = bid & 127;
        const int m0 = (r & 15) << 6, n0 = (r >> 4) << 6;
        const ushort* Ap = wb + (size_t)z * 1048576 + (size_t)m0 * 1024;  // [t][s]
        const ushort* Bp = vT + (size_t)n0 * 2048 + z * 1024;             // [e][s]
        float* C = out + (size_t)z * 524288;
        f32x4 acc[2][2] = {};
        gemm_tile(Ap, Bp, 1024, 2048, 16, smem, acc, tid);
        const int w = tid >> 6, wr = w >> 1, wc = w & 1;
        const int rb2 = (lane >> 4) << 2, cc = lane & 15;
#pragma unroll
        for (int fr = 0; fr < 2; ++fr)
#pragma unroll
            for (int fc = 0; fc < 2; ++fc) {
                int row = m0 + wr * 32 + fr * 16 + rb2;
                int col = n0 + wc * 32 + fc * 16 + cc;
#pragma unroll
                for (int rr = 0; rr < 4; ++rr) {
                    float sn, cs;
                    sincosf(acc[fr][fc][rr], &sn, &cs);
                    C[(size_t)(row + rr) * 512 + col] = cs * Aq - sn * Bq;
                }
            }
    }
}

// ---------------------------------------------------------------------------
extern "C" void kernel_launch(void* const* d_in, const int* in_sizes, int n_in,
                              void* d_out, int out_size, void* d_ws, size_t ws_size,
                              hipStream_t stream) {
    const float* x      = (const float*)d_in[0];
    const float* wq     = (const float*)d_in[1];
    const float* wk     = (const float*)d_in[2];
    const float* wv     = (const float*)d_in[3];
    const float* params = (const float*)d_in[4];
    float* out = (float*)d_out;

    char* base = (char*)d_ws;
    ushort* xb  = (ushort*)(base + 256);                // 2048x512
    ushort* wqb = xb + 2048 * 512;                      // 512x512
    ushort* wkb = wqb + 512 * 512;
    ushort* wvb = wkb + 512 * 512;
    ushort* qb  = wvb + 512 * 512;                      // 2048x512
    ushort* kb  = qb + 2048 * 512;                      // 2048x512
    ushort* vT  = kb + 2048 * 512;                      // 512x2048
    float*  sb  = (float*)(vT + 2048 * 512);            // 2x1024x1024 f32
    ushort* wb  = (ushort*)(sb + 2 * 1024 * 1024);      // 2x1024x1024 bf16

    void* args[15] = {
        (void*)&x, (void*)&wq, (void*)&wk, (void*)&wv, (void*)&params,
        (void*)&out, (void*)&xb, (void*)&wqb, (void*)&wkb, (void*)&wvb,
        (void*)&qb, (void*)&kb, (void*)&vT, (void*)&sb, (void*)&wb
    };
    hipLaunchCooperativeKernel((const void*)fused_all, dim3(GRID), dim3(256),
                               args, 0, stream);
}

// Round 12
// 96.549 us; speedup vs baseline: 3.7849x; 3.7849x over previous
//
#include <hip/hip_runtime.h>
#include <math.h>

typedef __attribute__((ext_vector_type(8))) short bf16x8;
typedef __attribute__((ext_vector_type(4))) float f32x4;

__device__ __forceinline__ ushort f2b(float f) {   // fp32 -> bf16 RNE
    unsigned u = __float_as_uint(f);
    return (ushort)((u + 0x7FFFu + ((u >> 16) & 1u)) >> 16);
}

// Direct global->LDS DMA, 16B per lane. LDS dest = uniform base + lane*16.
__device__ __forceinline__ void gl16(const ushort* g, ushort* l) {
    __builtin_amdgcn_global_load_lds((const __attribute__((address_space(1))) void*)g,
                                     (__attribute__((address_space(3))) void*)l, 16, 0, 0);
}

// Counted waits (T4): N = per-wave loads of ONE in-flight future tile.
__device__ __forceinline__ void wait4() { asm volatile("s_waitcnt vmcnt(4) lgkmcnt(0)" ::: "memory"); }
__device__ __forceinline__ void wait3() { asm volatile("s_waitcnt vmcnt(3) lgkmcnt(0)" ::: "memory"); }
__device__ __forceinline__ void wait0() { asm volatile("s_waitcnt vmcnt(0) lgkmcnt(0)" ::: "memory"); }

// ---------------------------------------------------------------------------
// Tile staging: rows x 64 bf16, row = 128B = 8 slots of 16B.
// Swizzle: LDS slot (r, s) holds logical col16 (s ^ (r&7)) [involution],
// applied on the global SOURCE address (LDS dest stays linear for DMA).
// ---------------------------------------------------------------------------
__device__ __forceinline__ void stage64(const ushort* g, int ld, ushort* lds,
                                        int w, int lane) {
    const int rsub = lane >> 3;
    const size_t coff = (size_t)(((lane & 7) ^ (rsub & 7)) * 8);
#pragma unroll
    for (int ii = 0; ii < 2; ++ii) {
        const int i = w * 2 + ii;
        gl16(g + (size_t)(i * 8 + rsub) * ld + coff, lds + i * 512);
    }
}
// 32-row tile: one gl16 per wave.
__device__ __forceinline__ void stage32(const ushort* g, int ld, ushort* lds,
                                        int w, int lane) {
    const int rsub = lane >> 3;
    const size_t coff = (size_t)(((lane & 7) ^ (rsub & 7)) * 8);
    gl16(g + (size_t)(w * 8 + rsub) * ld + coff, lds + w * 512);
}

// Read one 16x32 MFMA operand fragment (row0 multiple of 16), k-half c of BK=64.
__device__ __forceinline__ bf16x8 frag(const ushort* lds, int row0, int c, int lane) {
    const int r = row0 + (lane & 15);
    const int slot = (c * 4 + (lane >> 4)) ^ (r & 7);
    return *(const bf16x8*)(lds + (size_t)r * 64 + slot * 8);
}

// 64x64 block, 4 waves (2x2), wave-tile 32x32 = 2x2 frags. 8 MFMA / step.
__device__ __forceinline__ void compute64(const ushort* As, const ushort* Bs,
                                          f32x4 acc[2][2], int lane, int wr, int wc) {
#pragma unroll
    for (int c = 0; c < 2; ++c) {
        bf16x8 a[2], b[2];
#pragma unroll
        for (int f = 0; f < 2; ++f) {
            a[f] = frag(As, wr * 32 + f * 16, c, lane);
            b[f] = frag(Bs, wc * 32 + f * 16, c, lane);
        }
#pragma unroll
        for (int i = 0; i < 2; ++i)
#pragma unroll
            for (int j = 0; j < 2; ++j)
                acc[i][j] = __builtin_amdgcn_mfma_f32_16x16x32_bf16(a[i], b[j], acc[i][j], 0, 0, 0);
    }
}

// ---------------------------------------------------------------------------
// Fused: fp32->bf16 convert (y=0..3) + quantum constants (y=4, x=0).
// z_q(theta) = cos(theta)*A_q - sin(theta)*B_q collapses the circuit;
// ab[0..7]=A_q=<Z_q>_psi0, ab[8..15]=B_q=<X_q>_psi0.
// ---------------------------------------------------------------------------
__global__ __launch_bounds__(256) void cvtq_kernel(const float* __restrict__ x,
                                                   const float* __restrict__ wq,
                                                   const float* __restrict__ wk,
                                                   const float* __restrict__ wv,
                                                   const float* __restrict__ params,
                                                   ushort* __restrict__ xb,
                                                   ushort* __restrict__ wqb,
                                                   ushort* __restrict__ wkb,
                                                   ushort* __restrict__ wvb,
                                                   float* __restrict__ ab) {
    const int tid = threadIdx.x;
    if (blockIdx.y < 4) {
        const int z = blockIdx.y;
        const float* src = (z == 0) ? x : (z == 1) ? wq : (z == 2) ? wk : wv;
        ushort* dst = (z == 0) ? xb : (z == 1) ? wqb : (z == 2) ? wkb : wvb;
        const int n = (z == 0) ? (2048 * 512) : (512 * 512);
        const int i = (blockIdx.x * 256 + tid) * 8;
        if (i >= n) return;
        float4 v0 = *(const float4*)(src + i);
        float4 v1 = *(const float4*)(src + i + 4);
        ushort t[8] = {f2b(v0.x), f2b(v0.y), f2b(v0.z), f2b(v0.w),
                       f2b(v1.x), f2b(v1.y), f2b(v1.z), f2b(v1.w)};
        *(uint4*)(dst + i) = *(uint4*)t;
        return;
    }
    if (blockIdx.x != 0) return;
    __shared__ float st[256];
    __shared__ float red[64];
    st[tid] = (tid == 0) ? 1.0f : 0.0f;
    __syncthreads();
    for (int l = 0; l < 2; ++l) {
        for (int q = 0; q < 8; ++q) {
            float h = 0.5f * params[l * 8 + q];
            float c = cosf(h), s = sinf(h);
            int str = 1 << (7 - q);
            if ((tid & str) == 0) {
                float s0 = st[tid], s1 = st[tid + str];
                st[tid]       = c * s0 - s * s1;
                st[tid + str] = s * s0 + c * s1;
            }
            __syncthreads();
        }
        for (int q = 0; q < 8; ++q) {
            int tw = (q + 1) & 7;
            int cs = 1 << (7 - q), ts = 1 << (7 - tw);
            if ((tid & cs) && !(tid & ts)) {
                float a = st[tid], b = st[tid ^ ts];
                st[tid] = b;
                st[tid ^ ts] = a;
            }
            __syncthreads();
        }
    }
    const float amp = st[tid];
    float v[16];
#pragma unroll
    for (int q = 0; q < 8; ++q) {
        int str = 1 << (7 - q);
        v[q]     = amp * amp * ((tid & str) ? -1.0f : 1.0f);
        v[8 + q] = ((tid & str) == 0) ? 2.0f * amp * st[tid ^ str] : 0.0f;
    }
#pragma unroll
    for (int off = 32; off; off >>= 1)
#pragma unroll
        for (int q = 0; q < 16; ++q) v[q] += __shfl_xor(v[q], off);
    const int lane = tid & 63, wid = tid >> 6;
    if (lane == 0)
#pragma unroll
        for (int q = 0; q < 16; ++q) red[wid * 16 + q] = v[q];
    __syncthreads();
    if (tid < 16) ab[tid] = red[tid] + red[16 + tid] + red[32 + tid] + red[48 + tid];
}

// ---------------------------------------------------------------------------
// QKV. z=0/1: q,k[t][n] = x . W^T (M=2048,N=512). z=2: vT[e][s] = Wv . x^T.
// 64x64 tile, BK=64, 3-buffer counted-vmcnt pipeline (grid 768 = 3 blk/CU).
// ---------------------------------------------------------------------------
__global__ __launch_bounds__(256) void qkv_mfma(const ushort* __restrict__ xb,
                                                const ushort* __restrict__ wqb,
                                                const ushort* __restrict__ wkb,
                                                const ushort* __restrict__ wvb,
                                                ushort* __restrict__ qb,
                                                ushort* __restrict__ kb,
                                                ushort* __restrict__ vT) {
    __shared__ ushort lds[3][2 * 64 * 64];
    const int tid = threadIdx.x, lane = tid & 63, w = tid >> 6;
    const int wr = w >> 1, wc = w & 1;
    const int z = blockIdx.z;
    int m0, n0, ldc;
    const ushort *A, *B;
    ushort* C;
    if (z < 2) {
        m0 = blockIdx.x << 6;  n0 = blockIdx.y << 6;
        A = xb;  B = (z == 0) ? wqb : wkb;  C = (z == 0) ? qb : kb;  ldc = 512;
    } else {
        m0 = blockIdx.y << 6;  n0 = blockIdx.x << 6;
        A = wvb;  B = xb;  C = vT;  ldc = 2048;
    }
    const ushort* Ap = A + (size_t)m0 * 512;
    const ushort* Bp = B + (size_t)n0 * 512;
    stage64(Ap, 512, lds[0], w, lane);
    stage64(Bp, 512, lds[0] + 4096, w, lane);
    stage64(Ap + 64, 512, lds[1], w, lane);
    stage64(Bp + 64, 512, lds[1] + 4096, w, lane);
    f32x4 acc[2][2] = {};
    const int NT = 8;
    for (int t = 0; t < NT; ++t) {
        if (t < NT - 1) wait4(); else wait0();
        __builtin_amdgcn_s_barrier();
        __builtin_amdgcn_sched_barrier(0);
        if (t + 2 < NT) {
            ushort* nb = lds[(t + 2) % 3];
            stage64(Ap + (t + 2) * 64, 512, nb, w, lane);
            stage64(Bp + (t + 2) * 64, 512, nb + 4096, w, lane);
        }
        const ushort* cb = lds[t % 3];
        compute64(cb, cb + 4096, acc, lane, wr, wc);
    }
    const int rb2 = (lane >> 4) << 2, cc = lane & 15;
#pragma unroll
    for (int fr = 0; fr < 2; ++fr)
#pragma unroll
        for (int fc = 0; fc < 2; ++fc) {
            int row = m0 + wr * 32 + fr * 16 + rb2;
            int col = n0 + wc * 32 + fc * 16 + cc;
#pragma unroll
            for (int r = 0; r < 4; ++r)
                C[(size_t)(row + r) * ldc + col] = f2b(acc[fr][fc][r]);
        }
}

// ---------------------------------------------------------------------------
// Scores: S = (q.k^T)/sqrt(512), fp32 out. 64x64 tile, pipelined.
// ---------------------------------------------------------------------------
__global__ __launch_bounds__(256) void scores_mfma(const ushort* __restrict__ qb,
                                                   const ushort* __restrict__ kb,
                                                   float* __restrict__ sb) {
    __shared__ ushort lds[3][2 * 64 * 64];
    const int tid = threadIdx.x, lane = tid & 63, w = tid >> 6;
    const int wr = w >> 1, wc = w & 1;
    const int m0 = blockIdx.x << 6, n0 = blockIdx.y << 6, z = blockIdx.z;
    const ushort* Ap = qb + (size_t)z * 1024 * 512 + (size_t)m0 * 512;
    const ushort* Bp = kb + (size_t)z * 1024 * 512 + (size_t)n0 * 512;
    float* C = sb + (size_t)z * 1024 * 1024;
    stage64(Ap, 512, lds[0], w, lane);
    stage64(Bp, 512, lds[0] + 4096, w, lane);
    stage64(Ap + 64, 512, lds[1], w, lane);
    stage64(Bp + 64, 512, lds[1] + 4096, w, lane);
    f32x4 acc[2][2] = {};
    const int NT = 8;
    for (int t = 0; t < NT; ++t) {
        if (t < NT - 1) wait4(); else wait0();
        __builtin_amdgcn_s_barrier();
        __builtin_amdgcn_sched_barrier(0);
        if (t + 2 < NT) {
            ushort* nb = lds[(t + 2) % 3];
            stage64(Ap + (t + 2) * 64, 512, nb, w, lane);
            stage64(Bp + (t + 2) * 64, 512, nb + 4096, w, lane);
        }
        const ushort* cb = lds[t % 3];
        compute64(cb, cb + 4096, acc, lane, wr, wc);
    }
    const float scale = 0.044194173824159216f;   // 1/sqrt(512)
    const int rb2 = (lane >> 4) << 2, cc = lane & 15;
#pragma unroll
    for (int fr = 0; fr < 2; ++fr)
#pragma unroll
        for (int fc = 0; fc < 2; ++fc) {
            int row = m0 + wr * 32 + fr * 16 + rb2;
            int col = n0 + wc * 32 + fc * 16 + cc;
#pragma unroll
            for (int r = 0; r < 4; ++r)
                C[(size_t)(row + r) * 1024 + col] = acc[fr][fc][r] * scale;
        }
}

// ---------------------------------------------------------------------------
// Row softmax (1024 wide), fp32 in -> bf16 out.
// ---------------------------------------------------------------------------
__global__ __launch_bounds__(256) void softmax_kernel(const float* __restrict__ S,
                                                      ushort* __restrict__ W) {
    const int row = blockIdx.x, tid = threadIdx.x;
    const float* p = S + (size_t)row * 1024;
    float4 v = ((const float4*)p)[tid];
    float m = fmaxf(fmaxf(v.x, v.y), fmaxf(v.z, v.w));
#pragma unroll
    for (int off = 32; off; off >>= 1) m = fmaxf(m, __shfl_xor(m, off));
    __shared__ float sm[4];
    __shared__ float ss[4];
    const int wid = tid >> 6, lane = tid & 63;
    if (lane == 0) sm[wid] = m;
    __syncthreads();
    m = fmaxf(fmaxf(sm[0], sm[1]), fmaxf(sm[2], sm[3]));
    float e0 = expf(v.x - m), e1 = expf(v.y - m), e2 = expf(v.z - m), e3 = expf(v.w - m);
    float s = e0 + e1 + e2 + e3;
#pragma unroll
    for (int off = 32; off; off >>= 1) s += __shfl_xor(s, off);
    if (lane == 0) ss[wid] = s;
    __syncthreads();
    s = ss[0] + ss[1] + ss[2] + ss[3];
    float r = 1.0f / s;
    ushort4 o = {f2b(e0 * r), f2b(e1 * r), f2b(e2 * r), f2b(e3 * r)};
    ((ushort4*)(W + (size_t)row * 1024))[tid] = o;
}

// ---------------------------------------------------------------------------
// PV: o[t][e] = sum_s w[t,s] vT[e,s]; epilogue cos(o)A[e&7]-sin(o)B[e&7].
// 32x64 tile (grid 512 = 2 blk/CU), K=1024 (NT=16), counted-vmcnt pipeline.
// Per wave-tile 16x32: a-frag x 2 b-frags x 2 k-halves = 4 MFMA/step.
// ---------------------------------------------------------------------------
__global__ __launch_bounds__(256) void pv_mfma(const ushort* __restrict__ wb,
                                               const ushort* __restrict__ vT,
                                               float* __restrict__ out,
                                               const float* __restrict__ ab) {
    __shared__ ushort lds[3][6144];      // per buf: A 32x64 @0, B 64x64 @2048
    const int tid = threadIdx.x, lane = tid & 63, w = tid >> 6;
    const int wr = w >> 1, wc = w & 1;
    const int m0 = blockIdx.x << 5, n0 = blockIdx.y << 6, z = blockIdx.z;
    const ushort* Ap = wb + (size_t)z * 1048576 + (size_t)m0 * 1024;  // [t][s]
    const ushort* Bp = vT + (size_t)n0 * 2048 + z * 1024;             // [e][s]
    float* C = out + (size_t)z * 524288;
    stage32(Ap, 1024, lds[0], w, lane);
    stage64(Bp, 2048, lds[0] + 2048, w, lane);
    stage32(Ap + 64, 1024, lds[1], w, lane);
    stage64(Bp + 64, 2048, lds[1] + 2048, w, lane);
    f32x4 acc[2] = {};
    const int NT = 16;
    for (int t = 0; t < NT; ++t) {
        if (t < NT - 1) wait3(); else wait0();
        __builtin_amdgcn_s_barrier();
        __builtin_amdgcn_sched_barrier(0);
        if (t + 2 < NT) {
            ushort* nb = lds[(t + 2) % 3];
            stage32(Ap + (t + 2) * 64, 1024, nb, w, lane);
            stage64(Bp + (t + 2) * 64, 2048, nb + 2048, w, lane);
        }
        const ushort* cb = lds[t % 3];
#pragma unroll
        for (int c = 0; c < 2; ++c) {
            bf16x8 a = frag(cb, wr * 16, c, lane);
#pragma unroll
            for (int f = 0; f < 2; ++f) {
                bf16x8 b = frag(cb + 2048, wc * 32 + f * 16, c, lane);
                acc[f] = __builtin_amdgcn_mfma_f32_16x16x32_bf16(a, b, acc[f], 0, 0, 0);
            }
        }
    }
    const float Aq = ab[lane & 7], Bq = ab[8 + (lane & 7)];
    const int rb2 = (lane >> 4) << 2, cc = lane & 15;
#pragma unroll
    for (int fc = 0; fc < 2; ++fc) {
        int row = m0 + wr * 16 + rb2;
        int col = n0 + wc * 32 + fc * 16 + cc;
#pragma unroll
        for (int r = 0; r < 4; ++r) {
            float sn, cs;
            sincosf(acc[fc][r], &sn, &cs);
            C[(size_t)(row + r) * 512 + col] = cs * Aq - sn * Bq;
        }
    }
}

// ---------------------------------------------------------------------------
extern "C" void kernel_launch(void* const* d_in, const int* in_sizes, int n_in,
                              void* d_out, int out_size, void* d_ws, size_t ws_size,
                              hipStream_t stream) {
    const float* x      = (const float*)d_in[0];
    const float* Wq     = (const float*)d_in[1];
    const float* Wk     = (const float*)d_in[2];
    const float* Wv     = (const float*)d_in[3];
    const float* params = (const float*)d_in[4];
    float* out = (float*)d_out;

    char* base = (char*)d_ws;
    float*  ab  = (float*)base;                         // 64 B (pad to 256)
    ushort* xb  = (ushort*)(base + 256);                // 2048x512
    ushort* wqb = xb + 2048 * 512;                      // 512x512
    ushort* wkb = wqb + 512 * 512;
    ushort* wvb = wkb + 512 * 512;
    ushort* qb  = wvb + 512 * 512;                      // 2048x512
    ushort* kb  = qb + 2048 * 512;                      // 2048x512
    ushort* vT  = kb + 2048 * 512;                      // 512x2048
    float*  sb  = (float*)(vT + 2048 * 512);            // 2x1024x1024 f32
    ushort* wb  = (ushort*)(sb + 2 * 1024 * 1024);      // 2x1024x1024 bf16

    hipLaunchKernelGGL(cvtq_kernel, dim3(512, 5), dim3(256), 0, stream,
                       x, Wq, Wk, Wv, params, xb, wqb, wkb, wvb, ab);
    hipLaunchKernelGGL(qkv_mfma, dim3(32, 8, 3), dim3(256), 0, stream,
                       xb, wqb, wkb, wvb, qb, kb, vT);
    hipLaunchKernelGGL(scores_mfma, dim3(16, 16, 2), dim3(256), 0, stream, qb, kb, sb);
    hipLaunchKernelGGL(softmax_kernel, dim3(2048), dim3(256), 0, stream, sb, wb);
    hipLaunchKernelGGL(pv_mfma, dim3(32, 8, 2), dim3(256), 0, stream, wb, vT, out, ab);
}